// Round 1
// baseline (2230.231 us; speedup 1.0000x reference)
//
#include <hip/hip_runtime.h>

#define B_  128
#define T_  4096
#define F_  64
#define H_  128
#define NT  256   // 4 waves; wave w owns cols 32w..32w+31 of each gate
#define XGS 516   // padded xg row stride in f32 (512 + 4)

typedef _Float16 half8_t __attribute__((ext_vector_type(8)));
typedef _Float16 half4_t __attribute__((ext_vector_type(4)));
typedef float    f32x4   __attribute__((ext_vector_type(4)));

#define LOG2E_NEG  (-1.4426950408889634f)
#define LOG2E_NEG2 (-2.8853900817779268f)

__device__ __forceinline__ half4_t pack4(float4 v) {
  half4_t r;
  r[0] = (_Float16)v.x; r[1] = (_Float16)v.y;
  r[2] = (_Float16)v.z; r[3] = (_Float16)v.w;
  return r;
}

// LDS-only barrier (no vmcnt drain; global x loads stay in flight).
__device__ __forceinline__ void wg_barrier() {
  __asm__ volatile("s_waitcnt lgkmcnt(0)\n\ts_barrier" ::: "memory");
}

// Preacts arrive pre-scaled: x*(-log2e) for sigmoid gates, x*(-2log2e) for tanh.
__device__ __forceinline__ float sig_s(float xs) {
  return __builtin_amdgcn_rcpf(1.0f + __builtin_amdgcn_exp2f(xs));
}
__device__ __forceinline__ float tanh_s(float ys) {
  return 2.0f * __builtin_amdgcn_rcpf(1.0f + __builtin_amdgcn_exp2f(ys)) - 1.0f;
}

// Per step only the h-part (32 mfma/wave). Wih*x + bias is batched over time:
// every 16 steps one M=16 (16 timesteps) GEMM -> xg in LDS (fp32, pre-scaled).
// Pipeline over period P: consume xg(P); GEMM xg(P+1) at tau==0 (from xstage
// staged last period); global-load X(P+2) at tau==0, LDS-stage it at tau==8.
__global__ __launch_bounds__(NT, 1) void lstm_xg_kernel(
    const float* __restrict__ X,    // [B, T, F]
    const float* __restrict__ Wih,  // [4H, F]
    const float* __restrict__ Whh,  // [4H, H]
    const float* __restrict__ bih,  // [4H]
    const float* __restrict__ bhh,  // [4H]
    float* __restrict__ out)        // [B, H]
{
  const int tid  = threadIdx.x;
  const int b    = blockIdx.x;
  const int lane = tid & 63;
  const int w    = tid >> 6;     // wave 0..3
  const int lg   = lane >> 4;    // k-group / tau-group 0..3
  const int lc   = lane & 15;    // col-in-16 (also tau row in batch GEMM A)

  __shared__ __align__(16) _Float16 hbuf[2][H_];        // h ring (f16)
  __shared__ __align__(16) _Float16 xst[2][16 * 72];    // staged x, 16 tau x 64 (+8 pad) f16
  __shared__ __align__(16) float    xg[2][16 * XGS];    // xg[tau][col][gate] fp32, pre-scaled

  // ---- B-frags: Wf[g][u][c]; lane holds W[128g + 32w + 16u + lc][32c + 8lg + j],
  // j=0..7 (c=0..3 -> Whh, c=4..5 -> Wih), f32 -> f16, PRE-SCALED by the gate's
  // exp2 constant so the activation chain needs no multiply.
  half8_t Wf[4][2][6];
  float   bs[4][2];   // pre-scaled bias (C-init of the batch GEMM)
#pragma unroll
  for (int g = 0; g < 4; ++g) {
    const float s = (g == 2) ? LOG2E_NEG2 : LOG2E_NEG;
#pragma unroll
    for (int u = 0; u < 2; ++u) {
      const int row = 128 * g + 32 * w + 16 * u + lc;
      bs[g][u] = (bih[row] + bhh[row]) * s;
#pragma unroll
      for (int c = 0; c < 6; ++c) {
        const float* src = (c < 4) ? (Whh + (size_t)row * H_ + 32 * c + 8 * lg)
                                   : (Wih + (size_t)row * F_ + 32 * (c - 4) + 8 * lg);
        float4 lo = *(const float4*)(src);
        float4 hi = *(const float4*)(src + 4);
        half8_t v;
        v[0] = (_Float16)(lo.x * s); v[1] = (_Float16)(lo.y * s);
        v[2] = (_Float16)(lo.z * s); v[3] = (_Float16)(lo.w * s);
        v[4] = (_Float16)(hi.x * s); v[5] = (_Float16)(hi.y * s);
        v[6] = (_Float16)(hi.z * s); v[7] = (_Float16)(hi.w * s);
        Wf[g][u][c] = v;
      }
    }
  }

  const float* xbase = X + (size_t)b * T_ * F_;
  const int    tp    = tid >> 4;   // tau row this thread stages (0..15)
  const int    kp    = tid & 15;   // float4 chunk within row

  // ---- prologue: stage X(period 0) and X(period 1) to LDS f16
  {
    float4 v0 = ((const float4*)xbase)[0 * 256 + tid];
    float4 v1 = ((const float4*)xbase)[1 * 256 + tid];
    *(half4_t*)&xst[0][tp * 72 + 4 * kp] = pack4(v0);
    *(half4_t*)&xst[1][tp * 72 + 4 * kp] = pack4(v1);
  }
  wg_barrier();   // xst[0], xst[1] visible

  const f32x4 zf = {0.0f, 0.0f, 0.0f, 0.0f};

  // ---- GEMM xg(0) from xst[0] -> xg[0]
  {
    half8_t a0 = *(const half8_t*)&xst[0][lc * 72 + 8 * lg];        // k=0..31 slice
    half8_t a1 = *(const half8_t*)&xst[0][lc * 72 + 32 + 8 * lg];   // k=32..63 slice
#pragma unroll
    for (int g = 0; g < 4; ++g)
#pragma unroll
      for (int u = 0; u < 2; ++u) {
        f32x4 bi = {bs[g][u], bs[g][u], bs[g][u], bs[g][u]};
        f32x4 ab = __builtin_amdgcn_mfma_f32_16x16x32_f16(a0, Wf[g][u][4], bi, 0, 0, 0);
        ab       = __builtin_amdgcn_mfma_f32_16x16x32_f16(a1, Wf[g][u][5], ab, 0, 0, 0);
#pragma unroll
        for (int r = 0; r < 4; ++r)
          xg[0][(4 * lg + r) * XGS + (32 * w + 16 * u + lc) * 4 + g] = ab[r];
      }
  }
  wg_barrier();   // xg[0] visible

  f32x4 pre[4][2], pB[4][2];
#pragma unroll
  for (int g = 0; g < 4; ++g)
#pragma unroll
    for (int u = 0; u < 2; ++u) { pre[g][u] = zf; pB[g][u] = zf; }

  f32x4 xg4a = *(const f32x4*)&xg[0][0 * XGS + (32 * w + lc) * 4];        // t=0, col lo
  f32x4 xg4b = *(const f32x4*)&xg[0][0 * XGS + (32 * w + 16 + lc) * 4];   // t=0, col hi

  float cs0 = 0.0f, cs1 = 0.0f, hl0 = 0.0f, hl1 = 0.0f;
  float4 xv = {0.0f, 0.0f, 0.0f, 0.0f};

#pragma unroll 16
  for (int t = 0; t < T_; ++t) {
    const int buf = t & 1;
    const int P   = t >> 4;
    const int tau = t & 15;

    // ---- activation: preact = h-part (pre+pB) + xg (bias + scale folded in)
    float p00 = pre[0][0][0] + pB[0][0][0] + xg4a[0];
    float p10 = pre[1][0][0] + pB[1][0][0] + xg4a[1];
    float p20 = pre[2][0][0] + pB[2][0][0] + xg4a[2];
    float p30 = pre[3][0][0] + pB[3][0][0] + xg4a[3];
    float p01 = pre[0][1][0] + pB[0][1][0] + xg4b[0];
    float p11 = pre[1][1][0] + pB[1][1][0] + xg4b[1];
    float p21 = pre[2][1][0] + pB[2][1][0] + xg4b[2];
    float p31 = pre[3][1][0] + pB[3][1][0] + xg4b[3];

    float si0 = sig_s(p00), sf0 = sig_s(p10), sg0 = tanh_s(p20), so0 = sig_s(p30);
    float si1 = sig_s(p01), sf1 = sig_s(p11), sg1 = tanh_s(p21), so1 = sig_s(p31);

    cs0 = sf0 * cs0 + si0 * sg0;
    cs1 = sf1 * cs1 + si1 * sg1;
    float hn0 = so0 * tanh_s(cs0 * LOG2E_NEG2);
    float hn1 = so1 * tanh_s(cs1 * LOG2E_NEG2);
    hl0 = hn0; hl1 = hn1;

    if (lane < 16) {
      hbuf[buf][32 * w + lc]      = (_Float16)hn0;
      hbuf[buf][32 * w + 16 + lc] = (_Float16)hn1;
    }

    // ---- period work (wave-uniform, compile-time with unroll 16)
    if (tau == 0) {
      // batch GEMM xg(P+1) from xst[(P+1)&1] -> xg[(P+1)&1]
      const int sb = (P + 1) & 1;
      half8_t a0 = *(const half8_t*)&xst[sb][lc * 72 + 8 * lg];
      half8_t a1 = *(const half8_t*)&xst[sb][lc * 72 + 32 + 8 * lg];
#pragma unroll
      for (int g = 0; g < 4; ++g)
#pragma unroll
        for (int u = 0; u < 2; ++u) {
          f32x4 bi = {bs[g][u], bs[g][u], bs[g][u], bs[g][u]};
          f32x4 ab = __builtin_amdgcn_mfma_f32_16x16x32_f16(a0, Wf[g][u][4], bi, 0, 0, 0);
          ab       = __builtin_amdgcn_mfma_f32_16x16x32_f16(a1, Wf[g][u][5], ab, 0, 0, 0);
#pragma unroll
          for (int r = 0; r < 4; ++r)
            xg[sb][(4 * lg + r) * XGS + (32 * w + 16 * u + lc) * 4 + g] = ab[r];
        }
      // issue global loads for X(P+2); consumed at tau==8
      int Pn = P + 2; if (Pn > (T_ / 16 - 1)) Pn = T_ / 16 - 1;
      xv = ((const float4*)xbase)[(size_t)Pn * 256 + tid];
    }
    if (tau == 8) {
      // stage X(P+2) (loaded at tau==0) into xst[P&1] (X(P) is dead)
      *(half4_t*)&xst[P & 1][tp * 72 + 4 * kp] = pack4(xv);
    }

    wg_barrier();   // h_t (+ any xg/xst writes) visible

    // ---- post-barrier: h-frag reads + xg prefetch for t+1 + 32 h-mfmas
    half8_t ah0 = *(const half8_t*)&hbuf[buf][ 0 + 8 * lg];
    half8_t ah1 = *(const half8_t*)&hbuf[buf][32 + 8 * lg];
    half8_t ah2 = *(const half8_t*)&hbuf[buf][64 + 8 * lg];
    half8_t ah3 = *(const half8_t*)&hbuf[buf][96 + 8 * lg];

    const int tn   = t + 1;
    const int nb   = (tn >> 4) & 1;
    const int ntau = tn & 15;
    xg4a = *(const f32x4*)&xg[nb][ntau * XGS + (32 * w + lc) * 4];
    xg4b = *(const f32x4*)&xg[nb][ntau * XGS + (32 * w + 16 + lc) * 4];

#pragma unroll
    for (int g = 0; g < 4; ++g)
#pragma unroll
      for (int u = 0; u < 2; ++u) {
        f32x4 a   = __builtin_amdgcn_mfma_f32_16x16x32_f16(ah0, Wf[g][u][0], zf, 0, 0, 0);
        pre[g][u] = __builtin_amdgcn_mfma_f32_16x16x32_f16(ah1, Wf[g][u][1], a, 0, 0, 0);
        f32x4 a2  = __builtin_amdgcn_mfma_f32_16x16x32_f16(ah2, Wf[g][u][2], zf, 0, 0, 0);
        pB[g][u]  = __builtin_amdgcn_mfma_f32_16x16x32_f16(ah3, Wf[g][u][3], a2, 0, 0, 0);
      }
  }

  if (lane < 16) {
    out[(size_t)b * H_ + 32 * w + lc]      = hl0;
    out[(size_t)b * H_ + 32 * w + 16 + lc] = hl1;
  }
}

extern "C" void kernel_launch(void* const* d_in, const int* in_sizes, int n_in,
                              void* d_out, int out_size, void* d_ws, size_t ws_size,
                              hipStream_t stream) {
  const float* X   = (const float*)d_in[0];
  const float* Wih = (const float*)d_in[1];
  const float* Whh = (const float*)d_in[2];
  const float* bih = (const float*)d_in[3];
  const float* bhh = (const float*)d_in[4];
  float* out = (float*)d_out;

  lstm_xg_kernel<<<dim3(B_), dim3(NT), 0, stream>>>(X, Wih, Whh, bih, bhh, out);
}

// Round 2
// 1859.832 us; speedup vs baseline: 1.1992x; 1.1992x over previous
//
#include <hip/hip_runtime.h>

#define B_  128
#define T_  4096
#define F_  64
#define H_  128
#define NT  512   // 8 waves; wave w owns cols 16w..16w+15 of each gate
#define XGS 516   // padded xg row stride in f32 (512 + 4); keeps 16B alignment

typedef _Float16 half8_t __attribute__((ext_vector_type(8)));
typedef _Float16 half2_t __attribute__((ext_vector_type(2)));
typedef float    f32x4   __attribute__((ext_vector_type(4)));

#define L2N1 (-1.4426950408889634f)   // -log2(e)   : sigmoid gates
#define L2N2 (-2.8853900817779268f)   // -2*log2(e) : tanh gate & cell

__device__ __forceinline__ half2_t pack2(float a, float b) {
  half2_t r; r[0] = (_Float16)a; r[1] = (_Float16)b; return r;
}

// LDS-only barrier (no vmcnt drain; global x loads stay in flight).
__device__ __forceinline__ void wg_barrier() {
  __asm__ volatile("s_waitcnt lgkmcnt(0)\n\ts_barrier" ::: "memory");
}

// Per step only the h-part (16 mfma/wave). Wih*x + bias is batched over time:
// every 16 steps one M=16 (16 timesteps) GEMM -> xg in LDS (fp32, PRE-SCALED
// by the gate's exp2 constant). Pipeline over period P: consume xg(P); GEMM
// xg(P+1) + global-load X(P+2) post-barrier at tau==0; LDS-stage X at tau==8.
// Cell state kept in scaled domain csS = -2*log2e*c so tanh needs no mul.
__global__ __launch_bounds__(NT, 2) void lstm_xg_kernel(
    const float* __restrict__ X,    // [B, T, F]
    const float* __restrict__ Wih,  // [4H, F]
    const float* __restrict__ Whh,  // [4H, H]
    const float* __restrict__ bih,  // [4H]
    const float* __restrict__ bhh,  // [4H]
    float* __restrict__ out)        // [B, H]
{
  const int tid  = threadIdx.x;
  const int b    = blockIdx.x;
  const int lane = tid & 63;
  const int w    = tid >> 6;     // wave 0..7
  const int lg   = lane >> 4;    // k-group / tau-group 0..3
  const int lc   = lane & 15;    // col-in-16 (also tau row in batch GEMM A)

  __shared__ __align__(16) _Float16 hbuf[2][H_];        // h ring (f16)
  __shared__ __align__(16) _Float16 xst[2][16 * 72];    // staged x, 16 tau x 64 (+8 pad) f16
  __shared__ __align__(16) float    xg[2][16 * XGS];    // xg[tau][col][gate] fp32, pre-scaled

  // ---- B-frags: Wf[g][c]; lane holds W[128g + 16w + lc][32c + 8lg + j],
  // j=0..7 (c=0..3 -> Whh, c=4..5 -> Wih), f32 -> f16, PRE-SCALED by the
  // gate's exp2 constant so the activation chain needs no multiply.
  half8_t Wf[4][6];
  f32x4   xinit[4];   // pre-scaled bias, C-init of the batch GEMM
#pragma unroll
  for (int g = 0; g < 4; ++g) {
    const float s = (g == 2) ? L2N2 : L2N1;
    const int row = 128 * g + 16 * w + lc;
    const float bv = (bih[row] + bhh[row]) * s;
    f32x4 bi = {bv, bv, bv, bv};
    xinit[g] = bi;
#pragma unroll
    for (int c = 0; c < 6; ++c) {
      const float* src = (c < 4) ? (Whh + (size_t)row * H_ + 32 * c + 8 * lg)
                                 : (Wih + (size_t)row * F_ + 32 * (c - 4) + 8 * lg);
      float4 lo = *(const float4*)(src);
      float4 hi = *(const float4*)(src + 4);
      half8_t v;
      v[0] = (_Float16)(lo.x * s); v[1] = (_Float16)(lo.y * s);
      v[2] = (_Float16)(lo.z * s); v[3] = (_Float16)(lo.w * s);
      v[4] = (_Float16)(hi.x * s); v[5] = (_Float16)(hi.y * s);
      v[6] = (_Float16)(hi.z * s); v[7] = (_Float16)(hi.w * s);
      Wf[g][c] = v;
    }
  }

  const float* xbase = X + (size_t)b * T_ * F_;
  const int    tp    = tid >> 5;   // tau row this thread stages
  const int    kp    = tid & 31;   // f32-pair within row

  // ---- prologue: stage X(period 0) and X(period 1) to LDS f16
  {
    float2 v0 = ((const float2*)xbase)[0 * 512 + tid];
    float2 v1 = ((const float2*)xbase)[1 * 512 + tid];
    *(half2_t*)&xst[0][tp * 72 + 2 * kp] = pack2(v0.x, v0.y);
    *(half2_t*)&xst[1][tp * 72 + 2 * kp] = pack2(v1.x, v1.y);
  }
  wg_barrier();   // xst[0], xst[1] visible

  const f32x4 zf = {0.0f, 0.0f, 0.0f, 0.0f};

  // ---- GEMM xg(0) from xst[0] -> xg[0]
  {
    half8_t a0 = *(const half8_t*)&xst[0][lc * 72 + 8 * lg];        // k=0..31 slice
    half8_t a1 = *(const half8_t*)&xst[0][lc * 72 + 32 + 8 * lg];   // k=32..63 slice
#pragma unroll
    for (int g = 0; g < 4; ++g) {
      f32x4 ab = __builtin_amdgcn_mfma_f32_16x16x32_f16(a0, Wf[g][4], xinit[g], 0, 0, 0);
      ab       = __builtin_amdgcn_mfma_f32_16x16x32_f16(a1, Wf[g][5], ab, 0, 0, 0);
#pragma unroll
      for (int r = 0; r < 4; ++r)
        xg[0][(4 * lg + r) * XGS + (16 * w + lc) * 4 + g] = ab[r];
    }
  }
  wg_barrier();   // xg[0] visible

  f32x4 pre[4], pB[4];
#pragma unroll
  for (int g = 0; g < 4; ++g) { pre[g] = zf; pB[g] = zf; }
  f32x4 xg4 = *(const f32x4*)&xg[0][0 * XGS + (16 * w + lc) * 4];   // xg for t=0

  float csS = 0.0f, hl = 0.0f;   // cell state in scaled domain: csS = L2N2 * c
  float2 xv = {0.0f, 0.0f};

#pragma unroll 16
  for (int t = 0; t < T_; ++t) {
    const int buf = t & 1;
    const int P   = t >> 4;
    const int tau = t & 15;

    // ---- activation: preacts arrive pre-scaled (W, b, xg all folded)
    float p0 = pre[0][0] + pB[0][0] + xg4[0];   // i (sigmoid)
    float p1 = pre[1][0] + pB[1][0] + xg4[1];   // f (sigmoid)
    float p2 = pre[2][0] + pB[2][0] + xg4[2];   // g (tanh)
    float p3 = pre[3][0] + pB[3][0] + xg4[3];   // o (sigmoid)

    float si = __builtin_amdgcn_rcpf(1.0f + __builtin_amdgcn_exp2f(p0));
    float sf = __builtin_amdgcn_rcpf(1.0f + __builtin_amdgcn_exp2f(p1));
    float rg = __builtin_amdgcn_rcpf(1.0f + __builtin_amdgcn_exp2f(p2));  // (tanh+1)/2
    float so = __builtin_amdgcn_rcpf(1.0f + __builtin_amdgcn_exp2f(p3));

    // csS = sf*csS + L2N2*si*(2rg-1) = fma(sf, csS, fma(2ai, rg, -ai))
    float ai = si * L2N2;
    csS = fmaf(sf, csS, fmaf(ai + ai, rg, -ai));

    float so2 = so + so, son = -so;              // off-chain, hides exp2 latency
    float rh  = __builtin_amdgcn_rcpf(1.0f + __builtin_amdgcn_exp2f(csS));
    float hn  = fmaf(so2, rh, son);              // so * tanh(c)
    hl = hn;

    if (lane < 16) hbuf[buf][16 * w + lc] = (_Float16)hn;

    wg_barrier();   // h_t (+ previous xg/xst writes) visible

    // ---- post-barrier: h-frag reads first (longest latency on the chain)
    half8_t ah0 = *(const half8_t*)&hbuf[buf][ 0 + 8 * lg];
    half8_t ah1 = *(const half8_t*)&hbuf[buf][32 + 8 * lg];
    half8_t ah2 = *(const half8_t*)&hbuf[buf][64 + 8 * lg];
    half8_t ah3 = *(const half8_t*)&hbuf[buf][96 + 8 * lg];

    const int tn = t + 1;
    xg4 = *(const f32x4*)&xg[(tn >> 4) & 1][(tn & 15) * XGS + (16 * w + lc) * 4];

    // ---- period work, overlapped with the h-MFMA section (wave-uniform,
    // compile-time with unroll 16). Buffer lifetimes are barrier-separated:
    // xst[P&1] last read at step 16P-16, rewritten at 16P+8; xg[(P+1)&1]
    // written here (t=16P), first read at t=16P+15's prefetch.
    if (tau == 0) {
      const int sb = (P + 1) & 1;
      half8_t a0 = *(const half8_t*)&xst[sb][lc * 72 + 8 * lg];
      half8_t a1 = *(const half8_t*)&xst[sb][lc * 72 + 32 + 8 * lg];
#pragma unroll
      for (int g = 0; g < 4; ++g) {
        f32x4 ab = __builtin_amdgcn_mfma_f32_16x16x32_f16(a0, Wf[g][4], xinit[g], 0, 0, 0);
        ab       = __builtin_amdgcn_mfma_f32_16x16x32_f16(a1, Wf[g][5], ab, 0, 0, 0);
#pragma unroll
        for (int r = 0; r < 4; ++r)
          xg[sb][(4 * lg + r) * XGS + (16 * w + lc) * 4 + g] = ab[r];
      }
      // issue global loads for X(P+2); consumed at tau==8 (vmcnt not drained)
      int Pn = P + 2; if (Pn > (T_ / 16 - 1)) Pn = T_ / 16 - 1;
      xv = ((const float2*)xbase)[(size_t)Pn * 512 + tid];
    }
    if (tau == 8) {
      // stage X(P+2) (loaded at tau==0) into xst[P&1] (X(P) is dead)
      *(half2_t*)&xst[P & 1][tp * 72 + 2 * kp] = pack2(xv.x, xv.y);
    }

    // ---- 16 h-mfmas for step t+1 preacts
#pragma unroll
    for (int g = 0; g < 4; ++g) {
      f32x4 a  = __builtin_amdgcn_mfma_f32_16x16x32_f16(ah0, Wf[g][0], zf, 0, 0, 0);
      pre[g]   = __builtin_amdgcn_mfma_f32_16x16x32_f16(ah1, Wf[g][1], a, 0, 0, 0);
      f32x4 a2 = __builtin_amdgcn_mfma_f32_16x16x32_f16(ah2, Wf[g][2], zf, 0, 0, 0);
      pB[g]    = __builtin_amdgcn_mfma_f32_16x16x32_f16(ah3, Wf[g][3], a2, 0, 0, 0);
    }
  }

  if (lane < 16) out[(size_t)b * H_ + 16 * w + lc] = hl;
}

extern "C" void kernel_launch(void* const* d_in, const int* in_sizes, int n_in,
                              void* d_out, int out_size, void* d_ws, size_t ws_size,
                              hipStream_t stream) {
  const float* X   = (const float*)d_in[0];
  const float* Wih = (const float*)d_in[1];
  const float* Whh = (const float*)d_in[2];
  const float* bih = (const float*)d_in[3];
  const float* bhh = (const float*)d_in[4];
  float* out = (float*)d_out;

  lstm_xg_kernel<<<dim3(B_), dim3(NT), 0, stream>>>(X, Wih, Whh, bih, bhh, out);
}